// Round 1
// baseline (198.378 us; speedup 1.0000x reference)
//
#include <hip/hip_runtime.h>

// Problem constants (B=64, K=17, H=128, W=128, RATIO=0.25, SIGMA=2.0)
constexpr int HW      = 16384;            // 128*128
constexpr int NT      = 256;              // threads per block
constexpr int V4PT    = HW / (NT * 4);    // 16 float4 per thread
constexpr int NB      = 1024;             // histogram bins over [0,1)
constexpr int KTH     = HW - HW / 4;      // 12288 = 1-indexed k-th smallest (kthvalue)
constexpr int NSLICE  = 64 * 17;          // 1088 (b,k) slices
constexpr int NCANDM  = 256;              // candidate cap (expected ~16 per bin)

__global__ __launch_bounds__(NT) void wreg_slice(
    const float* __restrict__ pred,
    const float* __restrict__ tgt,
    float* __restrict__ partial)
{
    __shared__ int   hist[NB];
    __shared__ float redf[NT];
    __shared__ int   redi[NT];
    __shared__ float cands[NCANDM];
    __shared__ int   s_ncand;
    __shared__ int   s_bin;
    __shared__ int   s_before;
    __shared__ float s_thresh;
    __shared__ float s_cy, s_cx;

    const int t   = threadIdx.x;
    const int bid = blockIdx.x;
    const float4* t4 = reinterpret_cast<const float4*>(tgt)  + (size_t)bid * (HW / 4);
    const float4* p4 = reinterpret_cast<const float4*>(pred) + (size_t)bid * (HW / 4);

    for (int i = t; i < NB; i += NT) hist[i] = 0;
    if (t == 0) s_ncand = 0;
    __syncthreads();

    // ---- Pass 1: load target slice into registers; histogram + argmax ----
    float4 vreg[V4PT];
    float bmax = -1.0f;
    int   bmi  = 0;
    #pragma unroll
    for (int j = 0; j < V4PT; ++j) {
        const int vi = j * NT + t;
        float4 v = t4[vi];
        vreg[j] = v;
        const int base = vi * 4;
        float a[4] = {v.x, v.y, v.z, v.w};
        #pragma unroll
        for (int c = 0; c < 4; ++c) {
            float x = a[c];
            int b = (int)(x * (float)NB);
            b = b < 0 ? 0 : (b >= NB ? NB - 1 : b);
            atomicAdd(&hist[b], 1);
            if (x > bmax) { bmax = x; bmi = base + c; }  // per-thread indices increase -> keeps first
        }
    }

    // ---- Block argmax (first-index tie-break, matches jnp.argmax) ----
    redf[t] = bmax; redi[t] = bmi;
    __syncthreads();
    for (int s = NT / 2; s > 0; s >>= 1) {
        if (t < s) {
            float ov = redf[t + s]; int oi = redi[t + s];
            if (ov > redf[t] || (ov == redf[t] && oi < redi[t])) { redf[t] = ov; redi[t] = oi; }
        }
        __syncthreads();
    }
    if (t == 0) {
        int mi = redi[0];
        s_cy = (float)(mi >> 7);    // idx / 128
        s_cx = (float)(mi & 127);   // idx % 128
    }
    __syncthreads();   // also protects redi reuse below

    // ---- Histogram scan: locate bin containing the KTH-th smallest ----
    const int b0 = t * 4;
    const int h0 = hist[b0], h1 = hist[b0 + 1], h2 = hist[b0 + 2], h3 = hist[b0 + 3];
    const int ls = h0 + h1 + h2 + h3;
    redi[t] = ls;
    __syncthreads();
    for (int off = 1; off < NT; off <<= 1) {
        int add = (t >= off) ? redi[t - off] : 0;
        __syncthreads();
        redi[t] += add;
        __syncthreads();
    }
    int run = redi[t] - ls;   // exclusive prefix of this thread's 4 bins
    const int hc[4] = {h0, h1, h2, h3};
    #pragma unroll
    for (int c = 0; c < 4; ++c) {
        if (run < KTH && run + hc[c] >= KTH) { s_bin = b0 + c; s_before = run; }
        run += hc[c];
    }
    __syncthreads();

    // ---- Gather candidates of the selected bin (from registers) ----
    const int selbin = s_bin;
    #pragma unroll
    for (int j = 0; j < V4PT; ++j) {
        float4 v = vreg[j];
        float a[4] = {v.x, v.y, v.z, v.w};
        #pragma unroll
        for (int c = 0; c < 4; ++c) {
            float x = a[c];
            int b = (int)(x * (float)NB);
            b = b < 0 ? 0 : (b >= NB ? NB - 1 : b);
            if (b == selbin) {
                int pos = atomicAdd(&s_ncand, 1);
                if (pos < NCANDM) cands[pos] = x;
            }
        }
    }
    __syncthreads();

    // ---- Exact rank selection among candidates (bit-exact kthvalue) ----
    int m = s_ncand; if (m > NCANDM) m = NCANDM;
    const int r = KTH - s_before;   // 1-indexed rank within the bin
    for (int i = t; i < m; i += NT) {
        float ci = cands[i];
        int less = 0, eq = 0;
        for (int j2 = 0; j2 < m; ++j2) {
            float cj = cands[j2];
            less += (cj < ci) ? 1 : 0;
            eq   += (cj == ci) ? 1 : 0;
        }
        if (less < r && less + eq >= r) s_thresh = ci;  // any writer holds identical value
    }
    __syncthreads();

    // ---- Pass 2: masked MSE vs re-rendered Gaussian ----
    const float th = s_thresh;
    const float cy = s_cy, cx = s_cx;
    float sum = 0.0f;
    #pragma unroll
    for (int j = 0; j < V4PT; ++j) {
        const int vi = j * NT + t;
        float4 p = p4[vi];
        float4 v = vreg[j];
        const int base = vi * 4;
        float av[4] = {v.x, v.y, v.z, v.w};
        float ap[4] = {p.x, p.y, p.z, p.w};
        #pragma unroll
        for (int c = 0; c < 4; ++c) {
            float x = av[c];
            if (x > th) {
                const int idx = base + c;
                float dy = (float)(idx >> 7) - cy;
                float dx = (float)(idx & 127) - cx;
                float g  = __expf(-(dy * dy + dx * dx) * 0.125f);  // 1/(2*sigma^2) = 1/8
                float d  = ap[c] - g;
                sum += d * d;
            }
        }
    }
    // block reduce (wave64 shuffle + cross-wave LDS)
    for (int off = 32; off > 0; off >>= 1) sum += __shfl_down(sum, off);
    if ((t & 63) == 0) redf[t >> 6] = sum;
    __syncthreads();
    if (t == 0) partial[bid] = (redf[0] + redf[1]) + (redf[2] + redf[3]);
}

__global__ __launch_bounds__(NT) void wreg_final(
    const float* __restrict__ partial, float* __restrict__ out)
{
    __shared__ float red[4];
    const int t = threadIdx.x;
    float s = 0.0f;
    for (int i = t; i < NSLICE; i += NT) s += partial[i];
    for (int off = 32; off > 0; off >>= 1) s += __shfl_down(s, off);
    if ((t & 63) == 0) red[t >> 6] = s;
    __syncthreads();
    if (t == 0)
        out[0] = ((red[0] + red[1]) + (red[2] + red[3]))
                 * (1.0f / ((float)(HW / 4) * (float)NSLICE));  // / pxl_num / (B*K)
}

extern "C" void kernel_launch(void* const* d_in, const int* in_sizes, int n_in,
                              void* d_out, int out_size, void* d_ws, size_t ws_size,
                              hipStream_t stream)
{
    const float* pred = (const float*)d_in[0];   // "output" in reference
    const float* tgt  = (const float*)d_in[1];   // "target"
    float* partial = (float*)d_ws;               // 1088 floats
    float* out     = (float*)d_out;

    wreg_slice<<<NSLICE, NT, 0, stream>>>(pred, tgt, partial);
    wreg_final<<<1, NT, 0, stream>>>(partial, out);
}

// Round 2
// 178.784 us; speedup vs baseline: 1.1096x; 1.1096x over previous
//
#include <hip/hip_runtime.h>

// Problem: B=64, K=17, H=128, W=128, RATIO=0.25, SIGMA=2.0
constexpr int HW     = 16384;            // 128*128
constexpr int NT     = 512;              // threads per block
constexpr int NW     = NT / 64;          // 8 waves per block
constexpr int V4PT   = HW / (NT * 4);    // 8 float4 per thread
constexpr int KTH    = HW - HW / 4;      // 12288 = 1-indexed kth smallest (kthvalue)
constexpr int GTMAX  = HW - KTH;         // 4096 = #(v > thresh)
constexpr int NSLICE = 64 * 17;          // 1088 (b,k) slices
constexpr int NCANDM = 256;              // candidate buffer
constexpr int CAP    = 224;              // stop binary search when window <= CAP

__global__ __launch_bounds__(NT) void wreg_slice(
    const float* __restrict__ pred,
    const float* __restrict__ tgt,
    float* __restrict__ partial)
{
    __shared__ float redf[NW];
    __shared__ int   redi[NW];
    __shared__ int   wcnt[NW];
    __shared__ float cands[NCANDM];
    __shared__ int   s_ncand;
    __shared__ float s_thresh;

    const int t    = threadIdx.x;
    const int lane = t & 63;
    const int wid  = t >> 6;
    const int bid  = blockIdx.x;
    const float4* t4 = reinterpret_cast<const float4*>(tgt)  + (size_t)bid * (HW / 4);
    const float4* p4 = reinterpret_cast<const float4*>(pred) + (size_t)bid * (HW / 4);

    if (t == 0) s_ncand = 0;

    // ---- Load target slice into registers; per-thread argmax ----
    float4 vreg[V4PT];
    float bmax = -1.0f;
    int   bmi  = 0;
    #pragma unroll
    for (int j = 0; j < V4PT; ++j) {
        const int vi = j * NT + t;
        float4 v = t4[vi];
        vreg[j] = v;
        const int base = vi * 4;
        if (v.x > bmax) { bmax = v.x; bmi = base;     }
        if (v.y > bmax) { bmax = v.y; bmi = base + 1; }
        if (v.z > bmax) { bmax = v.z; bmi = base + 2; }
        if (v.w > bmax) { bmax = v.w; bmi = base + 3; }
    }

    // ---- Block argmax: wave shuffle reduce (first-index tie-break), then LDS ----
    #pragma unroll
    for (int off = 32; off > 0; off >>= 1) {
        float ov = __shfl_down(bmax, off);
        int   oi = __shfl_down(bmi, off);
        if (ov > bmax || (ov == bmax && oi < bmi)) { bmax = ov; bmi = oi; }
    }
    if (lane == 0) { redf[wid] = bmax; redi[wid] = bmi; }
    __syncthreads();
    float mv = redf[0]; int mi = redi[0];
    #pragma unroll
    for (int w = 1; w < NW; ++w) {
        if (redf[w] > mv || (redf[w] == mv && redi[w] < mi)) { mv = redf[w]; mi = redi[w]; }
    }
    const float cy = (float)(mi >> 7);    // idx / 128
    const float cx = (float)(mi & 127);   // idx % 128

    // ---- Exact kthvalue via binary search on the threshold value ----
    // Invariant: thresh in (lo, hi], g_lo = #(v > lo) >= GTMAX+1, g_hi = #(v > hi) <= GTMAX.
    float lo = -1.0f, hi = 1.0f;          // target values are in [0,1)
    int g_lo = HW, g_hi = 0;
    bool degen = false;
    while (g_lo - g_hi > CAP) {
        float mid = 0.5f * (lo + hi);
        if (!(mid > lo && mid < hi)) { degen = true; break; }  // adjacent floats: all window values == hi
        int cnt = 0;
        #pragma unroll
        for (int j = 0; j < V4PT; ++j) {
            float4 v = vreg[j];
            cnt += (v.x > mid) + (v.y > mid) + (v.z > mid) + (v.w > mid);
        }
        #pragma unroll
        for (int off = 32; off > 0; off >>= 1) cnt += __shfl_down(cnt, off);
        if (lane == 0) wcnt[wid] = cnt;
        __syncthreads();
        int total = 0;
        #pragma unroll
        for (int w = 0; w < NW; ++w) total += wcnt[w];   // uniform across all threads
        __syncthreads();                                  // protect wcnt for next iteration
        if (total >= GTMAX + 1) { lo = mid; g_lo = total; }
        else                    { hi = mid; g_hi = total; }
    }

    float th;
    if (degen) {
        th = hi;   // every value in (lo,hi] equals hi; g(hi)<=GTMAX, g(hi)+eq=g_lo>=GTMAX+1
    } else {
        // gather the <=CAP window candidates (s_ncand zeroed before loop barriers)
        #pragma unroll
        for (int j = 0; j < V4PT; ++j) {
            float4 v = vreg[j];
            float a[4] = {v.x, v.y, v.z, v.w};
            #pragma unroll
            for (int c = 0; c < 4; ++c) {
                float x = a[c];
                if (x > lo && x <= hi) {
                    int pos = atomicAdd(&s_ncand, 1);
                    cands[pos] = x;    // m = g_lo - g_hi <= CAP <= NCANDM
                }
            }
        }
        __syncthreads();
        const int m = s_ncand;
        const int r = GTMAX;   // want: g(th) <= GTMAX and g(th) + eq(th) >= GTMAX+1
        for (int i = t; i < m; i += NT) {
            float ci = cands[i];
            int gt = 0, eq = 0;
            for (int j2 = 0; j2 < m; ++j2) {
                float cj = cands[j2];
                gt += (cj > ci) ? 1 : 0;
                eq += (cj == ci) ? 1 : 0;
            }
            int gi = g_hi + gt;
            if (gi <= r && gi + eq >= r + 1) s_thresh = ci;  // unique distinct value; ties write same bits
        }
        __syncthreads();
        th = s_thresh;
    }

    // ---- Masked MSE vs re-rendered Gaussian ----
    float sum = 0.0f;
    #pragma unroll
    for (int j = 0; j < V4PT; ++j) {
        const int vi = j * NT + t;
        float4 p = p4[vi];
        float4 v = vreg[j];
        const int base = vi * 4;
        float av[4] = {v.x, v.y, v.z, v.w};
        float ap[4] = {p.x, p.y, p.z, p.w};
        #pragma unroll
        for (int c = 0; c < 4; ++c) {
            float x = av[c];
            if (x > th) {
                const int idx = base + c;
                float dy = (float)(idx >> 7) - cy;
                float dx = (float)(idx & 127) - cx;
                float g  = __expf(-(dy * dy + dx * dx) * 0.125f);  // 1/(2*sigma^2) = 1/8
                float d  = ap[c] - g;
                sum += d * d;
            }
        }
    }
    #pragma unroll
    for (int off = 32; off > 0; off >>= 1) sum += __shfl_down(sum, off);
    if (lane == 0) redf[wid] = sum;   // redf reads all completed before loop barriers
    __syncthreads();
    if (t == 0) {
        float s = 0.0f;
        #pragma unroll
        for (int w = 0; w < NW; ++w) s += redf[w];
        partial[bid] = s;
    }
}

__global__ __launch_bounds__(256) void wreg_final(
    const float* __restrict__ partial, float* __restrict__ out)
{
    __shared__ float red[4];
    const int t = threadIdx.x;
    float s = 0.0f;
    for (int i = t; i < NSLICE; i += 256) s += partial[i];
    for (int off = 32; off > 0; off >>= 1) s += __shfl_down(s, off);
    if ((t & 63) == 0) red[t >> 6] = s;
    __syncthreads();
    if (t == 0)
        out[0] = ((red[0] + red[1]) + (red[2] + red[3]))
                 * (1.0f / ((float)(HW / 4) * (float)NSLICE));  // / pxl_num / (B*K)
}

extern "C" void kernel_launch(void* const* d_in, const int* in_sizes, int n_in,
                              void* d_out, int out_size, void* d_ws, size_t ws_size,
                              hipStream_t stream)
{
    const float* pred = (const float*)d_in[0];   // "output" in reference
    const float* tgt  = (const float*)d_in[1];   // "target"
    float* partial = (float*)d_ws;               // 1088 floats of scratch
    float* out     = (float*)d_out;

    wreg_slice<<<NSLICE, NT, 0, stream>>>(pred, tgt, partial);
    wreg_final<<<1, 256, 0, stream>>>(partial, out);
}